// Round 3
// baseline (919.237 us; speedup 1.0000x reference)
//
#include <hip/hip_runtime.h>
#include <hip/hip_bf16.h>
#include <hip/hip_cooperative_groups.h>
#include <stdint.h>

namespace cg = cooperative_groups;

// Problem constants (QRNN layer: SEQ=4096, BATCH=8, IN=1024, HID=1024)
#define S_   4096
#define B_   8
#define IN_  1024
#define H_   1024
#define M_   (S_ * B_)     // 32768 rows of the GEMM (row = s*B + b)
#define N_   (3 * H_)      // 3072 output cols (Z | F | O)
#define K_   IN_           // 1024
#define CH_  (B_ * H_)     // 8192 independent scan channels
#define NC_  64            // scan chunks
#define T_   (S_ / NC_)    // 64 steps per chunk

typedef unsigned short u16;
typedef __bf16 bf16x8 __attribute__((ext_vector_type(8)));
typedef float  f32x4  __attribute__((ext_vector_type(4)));

__device__ __forceinline__ u16 f2bf(float f) {
  unsigned u = __float_as_uint(f);
  u += 0x7fffu + ((u >> 16) & 1u);   // round-to-nearest-even
  return (u16)(u >> 16);
}

__device__ __forceinline__ float sigmoid_(float x) { return 1.0f / (1.0f + __expf(-x)); }
__device__ __forceinline__ float tanh_(float x)    { return 2.0f / (1.0f + __expf(-2.0f * x)) - 1.0f; }

// ---- fused fp32 -> bf16 conversion for X and W in ONE launch ----------------
__global__ void cvt_all(const float* __restrict__ X, const float* __restrict__ W,
                        u16* __restrict__ Xb, u16* __restrict__ Wb) {
  const int nX = M_ * K_ / 8, nW = N_ * K_ / 8;
  int i = blockIdx.x * blockDim.x + threadIdx.x;
  const float* in; u16* out; int j;
  if (i < nX)           { in = X; out = Xb; j = i; }
  else if (i < nX + nW) { in = W; out = Wb; j = i - nX; }
  else return;
  const float4* p = (const float4*)in;
  float4 a = p[2 * j], b = p[2 * j + 1];
  alignas(16) u16 us[8] = {f2bf(a.x), f2bf(a.y), f2bf(a.z), f2bf(a.w),
                           f2bf(b.x), f2bf(b.y), f2bf(b.z), f2bf(b.w)};
  ((uint4*)out)[j] = *(const uint4*)us;
}

// =============================================================================
// 256x256 8-phase bf16 MFMA GEMM (NT), fused activation epilogue.
// (UNCHANGED from round 2 -- serves as the control for this round's A/B.)
// =============================================================================
#define SWZ(x) ((x) ^ (((x) >> 3) & 0x30))

#define DS_A(s, h, mh) do {                                                    \
  const char* base_ = (const char*)As_[(s)*2+(h)];                             \
  af[0] = *(const bf16x8*)(base_ + aoff[mh][0]);                               \
  af[1] = *(const bf16x8*)(base_ + aoff[mh][1]);                               \
  af[2] = *(const bf16x8*)(base_ + aoff[mh][2]);                               \
  af[3] = *(const bf16x8*)(base_ + aoff[mh][3]);                               \
} while (0)

#define DS_B(s, h) do {                                                        \
  const char* base_ = (const char*)Bs_[(s)*2+(h)];                             \
  bfr[0] = *(const bf16x8*)(base_ + boff[0]);                                  \
  bfr[1] = *(const bf16x8*)(base_ + boff[1]);                                  \
  bfr[2] = *(const bf16x8*)(base_ + boff[2]);                                  \
  bfr[3] = *(const bf16x8*)(base_ + boff[3]);                                  \
} while (0)

#define MMA(mh) do {                                                           \
  __builtin_amdgcn_s_setprio(1);                                              \
  _Pragma("unroll")                                                            \
  for (int fi_ = 0; fi_ < 4; ++fi_)                                            \
    _Pragma("unroll")                                                          \
    for (int fj_ = 0; fj_ < 4; ++fj_)                                          \
      acc[(mh)*4+fi_][fj_] = __builtin_amdgcn_mfma_f32_16x16x32_bf16(          \
          af[fi_], bfr[fj_], acc[(mh)*4+fi_][fj_], 0, 0, 0);                   \
  __builtin_amdgcn_s_setprio(0);                                              \
} while (0)

#define PH_SYNC() do {                                                         \
  asm volatile("" ::: "memory");                                               \
  __builtin_amdgcn_s_barrier();                                                \
  asm volatile("s_waitcnt lgkmcnt(0)" ::: "memory");                           \
} while (0)

#define PH_END() do {                                                          \
  asm volatile("" ::: "memory");                                               \
  __builtin_amdgcn_s_barrier();                                                \
} while (0)

#define VW(n) asm volatile("s_waitcnt vmcnt(" #n ")" ::: "memory")

__global__ __launch_bounds__(512, 2) void gemm_act(
    const u16* __restrict__ Ab, const u16* __restrict__ Bb,
    const float* __restrict__ bias,
    float* __restrict__ zt,   // tanh(Z)  -> ws        [M_, H_]
    float* __restrict__ Cf,   // sigm(F)  -> C region  [M_, H_]
    float* __restrict__ Ho) { // sigm(O)  -> H region  [M_, H_]
  __shared__ alignas(16) u16 As_[4][8192];
  __shared__ alignas(16) u16 Bs_[4][8192];

  const int tid = threadIdx.x;
  const int w = tid >> 6, l = tid & 63;
  const int m0 = blockIdx.y * 256, n0 = blockIdx.x * 256;
  const int wmo = (w >> 2) * 128, wno = (w & 3) * 64;
  const int lr = l & 15, lq = l >> 4;

  const int D0b  = w * 1024 + l * 16;
  const int row0 = D0b >> 6;
  const int c0   = (SWZ(D0b) & 63) >> 1;

  int aoff[2][4], boff[4];
#pragma unroll
  for (int mh = 0; mh < 2; ++mh)
#pragma unroll
    for (int fi = 0; fi < 4; ++fi)
      aoff[mh][fi] = SWZ((wmo + (mh * 4 + fi) * 16 + lr) * 64 + lq * 16);
#pragma unroll
  for (int fj = 0; fj < 4; ++fj)
    boff[fj] = SWZ((wno + fj * 16 + lr) * 64 + lq * 16);

  auto stage = [&](const u16* __restrict__ G, int rb, int tt, int hh, u16* dstp) {
    const u16* s0 = G + (size_t)(rb + row0) * K_ + (tt * 64 + hh * 32 + c0);
    __builtin_amdgcn_global_load_lds(
        (const __attribute__((address_space(1))) void*)s0,
        (__attribute__((address_space(3))) void*)(dstp + (D0b >> 1)), 16, 0, 0);
    const u16* s1 = s0 + (size_t)128 * K_;
    __builtin_amdgcn_global_load_lds(
        (const __attribute__((address_space(1))) void*)s1,
        (__attribute__((address_space(3))) void*)(dstp + (D0b >> 1) + 4096), 16, 0, 0);
  };

  f32x4 acc[8][4] = {};
  bf16x8 af[4], bfr[4];

  stage(Ab, m0, 0, 0, As_[0]); stage(Bb, n0, 0, 0, Bs_[0]);
  stage(Ab, m0, 0, 1, As_[1]); stage(Bb, n0, 0, 1, Bs_[1]);
  stage(Ab, m0, 1, 0, As_[2]); stage(Bb, n0, 1, 0, Bs_[2]);
  VW(4);
  PH_END();

  for (int i = 0; i < 7; ++i) {
    const int t1 = 2 * i + 1, t2 = 2 * i + 2, t3 = 2 * i + 3;
    DS_A(0, 0, 0); DS_B(0, 0); stage(Ab, m0, t1, 1, As_[3]);
    PH_SYNC(); MMA(0); PH_END();
    DS_A(0, 0, 1);             stage(Bb, n0, t1, 1, Bs_[3]);
    PH_SYNC(); MMA(1); PH_END();
    DS_A(0, 1, 0); DS_B(0, 1); stage(Ab, m0, t2, 0, As_[0]);
    PH_SYNC(); MMA(0); PH_END();
    DS_A(0, 1, 1);             stage(Bb, n0, t2, 0, Bs_[0]); VW(4);
    PH_SYNC(); MMA(1); PH_END();
    DS_A(1, 0, 0); DS_B(1, 0); stage(Ab, m0, t2, 1, As_[1]);
    PH_SYNC(); MMA(0); PH_END();
    DS_A(1, 0, 1);             stage(Bb, n0, t2, 1, Bs_[1]);
    PH_SYNC(); MMA(1); PH_END();
    DS_A(1, 1, 0); DS_B(1, 1); stage(Ab, m0, t3, 0, As_[2]);
    PH_SYNC(); MMA(0); PH_END();
    DS_A(1, 1, 1);             stage(Bb, n0, t3, 0, Bs_[2]); VW(4);
    PH_SYNC(); MMA(1); PH_END();
  }

  DS_A(0, 0, 0); DS_B(0, 0); stage(Ab, m0, 15, 1, As_[3]);
  PH_SYNC(); MMA(0); PH_END();
  DS_A(0, 0, 1);             stage(Bb, n0, 15, 1, Bs_[3]);
  PH_SYNC(); MMA(1); PH_END();
  DS_A(0, 1, 0); DS_B(0, 1);
  PH_SYNC(); MMA(0); PH_END();
  DS_A(0, 1, 1); VW(0);
  PH_SYNC(); MMA(1); PH_END();
  DS_A(1, 0, 0); DS_B(1, 0);
  PH_SYNC(); MMA(0); PH_END();
  DS_A(1, 0, 1);
  PH_SYNC(); MMA(1); PH_END();
  DS_A(1, 1, 0); DS_B(1, 1);
  PH_SYNC(); MMA(0); PH_END();
  DS_A(1, 1, 1);
  PH_SYNC(); MMA(1); PH_END();

  const int seg = n0 >> 10;
  const int nh0 = (n0 & 1023) + wno;
  float* dst = (seg == 0) ? zt : (seg == 1 ? Cf : Ho);
#pragma unroll
  for (int fj = 0; fj < 4; ++fj) {
    const int nn = nh0 + fj * 16 + lr;
    const float bv = bias[seg * 1024 + nn];
#pragma unroll
    for (int fi = 0; fi < 8; ++fi) {
#pragma unroll
      for (int rr = 0; rr < 4; ++rr) {
        const int mm = m0 + wmo + fi * 16 + lq * 4 + rr;
        const float v = acc[fi][fj][rr] + bv;
        dst[(size_t)mm * H_ + nn] = (seg == 0) ? tanh_(v) : sigmoid_(v);
      }
    }
  }
}

// =============================================================================
// Cooperative fused scan: passA -> grid.sync -> per-block combine -> passB.
// Bit-identical op order to the previous scanA/scanComb/scanB sequence.
// =============================================================================
__global__ void fused_scan(float* __restrict__ Cf,        // in: sigm(F), out: C
                           const float* __restrict__ zt,  // tanh(Z)
                           float* __restrict__ Ho,        // in: sigm(O), out: H
                           float* __restrict__ Clast,     // [CH_]
                           const float* __restrict__ hidden,
                           float* __restrict__ ckA, float* __restrict__ ckC) {
  cg::grid_group grid = cg::this_grid();
  const int ch2 = blockIdx.x * 256 + threadIdx.x;   // float2 channel index
  const int j   = blockIdx.y;
  const float2* Cf2c = (const float2*)Cf;
  const float2* zt2  = (const float2*)zt;

  // ---- pass A: chunk-local (prod(1-f), c_end with c_in = 0)
  size_t base2 = (size_t)j * T_ * (CH_ / 2) + ch2;
  float2 A = {1.f, 1.f}, c = {0.f, 0.f};
  for (int tt = 0; tt < T_; ++tt) {
    const float2 f = Cf2c[base2];
    const float2 z = zt2[base2];
    const float omx = 1.f - f.x, omy = 1.f - f.y;
    c.x = f.x * z.x + omx * c.x;
    c.y = f.y * z.y + omy * c.y;
    A.x *= omx;
    A.y *= omy;
    base2 += CH_ / 2;
  }
  ((float2*)ckA)[(size_t)j * (CH_ / 2) + ch2] = A;
  ((float2*)ckC)[(size_t)j * (CH_ / 2) + ch2] = c;

  grid.sync();

  // ---- redundant combine: carry into chunk j for this thread's 2 channels.
  // Reads are L2-resident (ckA/ckC = 4 MB); identical op order to scanComb.
  float2 cin = ((const float2*)hidden)[ch2];
  const float2* a2 = (const float2*)ckA;
  const float2* c2 = (const float2*)ckC;
  for (int jp = 0; jp < j; ++jp) {
    const float2 Aj = a2[(size_t)jp * (CH_ / 2) + ch2];
    const float2 Cj = c2[(size_t)jp * (CH_ / 2) + ch2];
    cin.x = Cj.x + Aj.x * cin.x;
    cin.y = Cj.y + Aj.y * cin.y;
  }

  // ---- pass B: replay with true carry; write C and H in place
  float2 cc = cin;
  base2 = (size_t)j * T_ * (CH_ / 2) + ch2;
  float2* Cf2 = (float2*)Cf;
  float2* Ho2 = (float2*)Ho;
  for (int tt = 0; tt < T_; ++tt) {
    const float2 f  = Cf2[base2];
    const float2 z  = zt2[base2];
    const float2 so = Ho2[base2];
    cc.x = f.x * z.x + (1.f - f.x) * cc.x;
    cc.y = f.y * z.y + (1.f - f.y) * cc.y;
    Cf2[base2] = cc;
    Ho2[base2] = float2{so.x * cc.x, so.y * cc.y};
    base2 += CH_ / 2;
  }
  if (j == NC_ - 1) ((float2*)Clast)[ch2] = cc;
}

// ---- fallback (non-cooperative) scan kernels, kept for safety ---------------
__global__ void scanA(const float* __restrict__ Cf, const float* __restrict__ zt,
                      float* __restrict__ ckA, float* __restrict__ ckC) {
  const int ch2 = blockIdx.x * 256 + threadIdx.x;
  const int j   = blockIdx.y;
  size_t base2 = (size_t)j * T_ * (CH_ / 2) + ch2;
  const float2* Cf2 = (const float2*)Cf;
  const float2* zt2 = (const float2*)zt;
  float2 A = {1.f, 1.f}, c = {0.f, 0.f};
  for (int tt = 0; tt < T_; ++tt) {
    const float2 f = Cf2[base2];
    const float2 z = zt2[base2];
    const float omx = 1.f - f.x, omy = 1.f - f.y;
    c.x = f.x * z.x + omx * c.x;
    c.y = f.y * z.y + omy * c.y;
    A.x *= omx;
    A.y *= omy;
    base2 += CH_ / 2;
  }
  ((float2*)ckA)[(size_t)j * (CH_ / 2) + ch2] = A;
  ((float2*)ckC)[(size_t)j * (CH_ / 2) + ch2] = c;
}

__global__ void scanComb(const float* __restrict__ ckA, const float* __restrict__ ckC,
                         const float* __restrict__ hidden, float* __restrict__ carry) {
  const int ch = blockIdx.x * 64 + threadIdx.x;
  float c = hidden[ch];
  for (int j = 0; j < NC_; ++j) {
    carry[j * CH_ + ch] = c;
    c = ckC[j * CH_ + ch] + ckA[j * CH_ + ch] * c;
  }
}

__global__ void scanB(float* __restrict__ Cf, const float* __restrict__ zt,
                      float* __restrict__ Ho, float* __restrict__ Clast,
                      const float* __restrict__ carry) {
  const int ch2 = blockIdx.x * 256 + threadIdx.x;
  const int j   = blockIdx.y;
  size_t base2 = (size_t)j * T_ * (CH_ / 2) + ch2;
  float2* Cf2 = (float2*)Cf;
  const float2* zt2 = (const float2*)zt;
  float2* Ho2 = (float2*)Ho;
  float2 c = ((const float2*)carry)[(size_t)j * (CH_ / 2) + ch2];
  for (int tt = 0; tt < T_; ++tt) {
    const float2 f  = Cf2[base2];
    const float2 z  = zt2[base2];
    const float2 so = Ho2[base2];
    c.x = f.x * z.x + (1.f - f.x) * c.x;
    c.y = f.y * z.y + (1.f - f.y) * c.y;
    Cf2[base2] = c;
    Ho2[base2] = float2{so.x * c.x, so.y * c.y};
    base2 += CH_ / 2;
  }
  if (j == NC_ - 1) ((float2*)Clast)[ch2] = c;
}

extern "C" void kernel_launch(void* const* d_in, const int* in_sizes, int n_in,
                              void* d_out, int out_size, void* d_ws, size_t ws_size,
                              hipStream_t stream) {
  const float* X    = (const float*)d_in[0];   // [S,B,IN]
  const float* hid  = (const float*)d_in[1];   // [B,H]
  const float* W    = (const float*)d_in[2];   // [3H,IN]
  const float* bias = (const float*)d_in[3];   // [3H]

  float* out   = (float*)d_out;
  float* Ho    = out;                          // H       [S,B,H]
  float* Clast = out + (size_t)M_ * H_;        // C[-1:]  [1,B,H]
  float* Cf    = Clast + CH_;                  // C       [S,B,H]

  char* ws = (char*)d_ws;
  u16*  Xb    = (u16*)ws;                      //  67108864 B bf16 X
  u16*  Wb    = (u16*)(ws + 67108864);         //   6291456 B bf16 W
  float* zt   = (float*)(ws + 73400320);       // 134217728 B tanh(Z)
  float* ckA  = (float*)(ws + 207618048);      //   2097152 B
  float* ckC  = (float*)(ws + 209715200);      //   2097152 B
  float* carry= (float*)(ws + 211812352);      //   2097152 B  (fallback only)

  const int nAll = M_ * K_ / 8 + N_ * K_ / 8;
  cvt_all<<<(nAll + 255) / 256, 256, 0, stream>>>(X, W, Xb, Wb);
  gemm_act<<<dim3(N_ / 256, M_ / 256), 512, 0, stream>>>(Xb, Wb, bias, zt, Cf, Ho);

  {
    float* CfA = Cf; const float* ztA = zt; float* HoA = Ho; float* ClA = Clast;
    const float* hiA = hid; float* ckAA = ckA; float* ckCA = ckC;
    void* args[] = {&CfA, &ztA, &HoA, &ClA, &hiA, &ckAA, &ckCA};
    hipError_t e = hipLaunchCooperativeKernel((const void*)fused_scan,
                                              dim3(CH_ / 512, NC_), dim3(256),
                                              args, 0, stream);
    if (e != hipSuccess) {
      // fallback: original 3-kernel scan pipeline
      scanA<<<dim3(CH_ / 512, NC_), 256, 0, stream>>>(Cf, zt, ckA, ckC);
      scanComb<<<CH_ / 64, 64, 0, stream>>>(ckA, ckC, hid, carry);
      scanB<<<dim3(CH_ / 512, NC_), 256, 0, stream>>>(Cf, zt, Ho, Clast, carry);
    }
  }
}

// Round 4
// 792.032 us; speedup vs baseline: 1.1606x; 1.1606x over previous
//
#include <hip/hip_runtime.h>
#include <hip/hip_bf16.h>
#include <stdint.h>

// Problem constants (QRNN layer: SEQ=4096, BATCH=8, IN=1024, HID=1024)
#define S_   4096
#define B_   8
#define IN_  1024
#define H_   1024
#define M_   (S_ * B_)     // 32768 rows of the GEMM (row = s*B + b)
#define N_   (3 * H_)      // 3072 output cols (Z | F | O)
#define K_   IN_           // 1024
#define CH_  (B_ * H_)     // 8192 independent scan channels
#define NC_  64            // scan chunks
#define T_   (S_ / NC_)    // 64 steps per chunk

typedef unsigned short u16;
typedef __bf16 bf16x8 __attribute__((ext_vector_type(8)));
typedef float  f32x4  __attribute__((ext_vector_type(4)));

__device__ __forceinline__ u16 f2bf(float f) {
  unsigned u = __float_as_uint(f);
  u += 0x7fffu + ((u >> 16) & 1u);   // round-to-nearest-even
  return (u16)(u >> 16);
}

__device__ __forceinline__ float sigmoid_(float x) { return 1.0f / (1.0f + __expf(-x)); }
__device__ __forceinline__ float tanh_(float x)    { return 2.0f / (1.0f + __expf(-2.0f * x)) - 1.0f; }

// ---- fused fp32 -> bf16 conversion for X and W in ONE launch ----------------
__global__ void cvt_all(const float* __restrict__ X, const float* __restrict__ W,
                        u16* __restrict__ Xb, u16* __restrict__ Wb) {
  const int nX = M_ * K_ / 8, nW = N_ * K_ / 8;
  int i = blockIdx.x * blockDim.x + threadIdx.x;
  const float* in; u16* out; int j;
  if (i < nX)           { in = X; out = Xb; j = i; }
  else if (i < nX + nW) { in = W; out = Wb; j = i - nX; }
  else return;
  const float4* p = (const float4*)in;
  float4 a = p[2 * j], b = p[2 * j + 1];
  alignas(16) u16 us[8] = {f2bf(a.x), f2bf(a.y), f2bf(a.z), f2bf(a.w),
                           f2bf(b.x), f2bf(b.y), f2bf(b.z), f2bf(b.w)};
  ((uint4*)out)[j] = *(const uint4*)us;
}

// =============================================================================
// 256x256 8-phase bf16 MFMA GEMM (NT), fused activation epilogue.
// (UNCHANGED -- control.)
// =============================================================================
#define SWZ(x) ((x) ^ (((x) >> 3) & 0x30))

#define DS_A(s, h, mh) do {                                                    \
  const char* base_ = (const char*)As_[(s)*2+(h)];                             \
  af[0] = *(const bf16x8*)(base_ + aoff[mh][0]);                               \
  af[1] = *(const bf16x8*)(base_ + aoff[mh][1]);                               \
  af[2] = *(const bf16x8*)(base_ + aoff[mh][2]);                               \
  af[3] = *(const bf16x8*)(base_ + aoff[mh][3]);                               \
} while (0)

#define DS_B(s, h) do {                                                        \
  const char* base_ = (const char*)Bs_[(s)*2+(h)];                             \
  bfr[0] = *(const bf16x8*)(base_ + boff[0]);                                  \
  bfr[1] = *(const bf16x8*)(base_ + boff[1]);                                  \
  bfr[2] = *(const bf16x8*)(base_ + boff[2]);                                  \
  bfr[3] = *(const bf16x8*)(base_ + boff[3]);                                  \
} while (0)

#define MMA(mh) do {                                                           \
  __builtin_amdgcn_s_setprio(1);                                              \
  _Pragma("unroll")                                                            \
  for (int fi_ = 0; fi_ < 4; ++fi_)                                            \
    _Pragma("unroll")                                                          \
    for (int fj_ = 0; fj_ < 4; ++fj_)                                          \
      acc[(mh)*4+fi_][fj_] = __builtin_amdgcn_mfma_f32_16x16x32_bf16(          \
          af[fi_], bfr[fj_], acc[(mh)*4+fi_][fj_], 0, 0, 0);                   \
  __builtin_amdgcn_s_setprio(0);                                              \
} while (0)

#define PH_SYNC() do {                                                         \
  asm volatile("" ::: "memory");                                               \
  __builtin_amdgcn_s_barrier();                                                \
  asm volatile("s_waitcnt lgkmcnt(0)" ::: "memory");                           \
} while (0)

#define PH_END() do {                                                          \
  asm volatile("" ::: "memory");                                               \
  __builtin_amdgcn_s_barrier();                                                \
} while (0)

#define VW(n) asm volatile("s_waitcnt vmcnt(" #n ")" ::: "memory")

__global__ __launch_bounds__(512, 2) void gemm_act(
    const u16* __restrict__ Ab, const u16* __restrict__ Bb,
    const float* __restrict__ bias,
    float* __restrict__ zt,   // tanh(Z)  -> ws        [M_, H_]
    float* __restrict__ Cf,   // sigm(F)  -> C region  [M_, H_]
    float* __restrict__ Ho) { // sigm(O)  -> H region  [M_, H_]
  __shared__ alignas(16) u16 As_[4][8192];
  __shared__ alignas(16) u16 Bs_[4][8192];

  const int tid = threadIdx.x;
  const int w = tid >> 6, l = tid & 63;
  const int m0 = blockIdx.y * 256, n0 = blockIdx.x * 256;
  const int wmo = (w >> 2) * 128, wno = (w & 3) * 64;
  const int lr = l & 15, lq = l >> 4;

  const int D0b  = w * 1024 + l * 16;
  const int row0 = D0b >> 6;
  const int c0   = (SWZ(D0b) & 63) >> 1;

  int aoff[2][4], boff[4];
#pragma unroll
  for (int mh = 0; mh < 2; ++mh)
#pragma unroll
    for (int fi = 0; fi < 4; ++fi)
      aoff[mh][fi] = SWZ((wmo + (mh * 4 + fi) * 16 + lr) * 64 + lq * 16);
#pragma unroll
  for (int fj = 0; fj < 4; ++fj)
    boff[fj] = SWZ((wno + fj * 16 + lr) * 64 + lq * 16);

  auto stage = [&](const u16* __restrict__ G, int rb, int tt, int hh, u16* dstp) {
    const u16* s0 = G + (size_t)(rb + row0) * K_ + (tt * 64 + hh * 32 + c0);
    __builtin_amdgcn_global_load_lds(
        (const __attribute__((address_space(1))) void*)s0,
        (__attribute__((address_space(3))) void*)(dstp + (D0b >> 1)), 16, 0, 0);
    const u16* s1 = s0 + (size_t)128 * K_;
    __builtin_amdgcn_global_load_lds(
        (const __attribute__((address_space(1))) void*)s1,
        (__attribute__((address_space(3))) void*)(dstp + (D0b >> 1) + 4096), 16, 0, 0);
  };

  f32x4 acc[8][4] = {};
  bf16x8 af[4], bfr[4];

  stage(Ab, m0, 0, 0, As_[0]); stage(Bb, n0, 0, 0, Bs_[0]);
  stage(Ab, m0, 0, 1, As_[1]); stage(Bb, n0, 0, 1, Bs_[1]);
  stage(Ab, m0, 1, 0, As_[2]); stage(Bb, n0, 1, 0, Bs_[2]);
  VW(4);
  PH_END();

  for (int i = 0; i < 7; ++i) {
    const int t1 = 2 * i + 1, t2 = 2 * i + 2, t3 = 2 * i + 3;
    DS_A(0, 0, 0); DS_B(0, 0); stage(Ab, m0, t1, 1, As_[3]);
    PH_SYNC(); MMA(0); PH_END();
    DS_A(0, 0, 1);             stage(Bb, n0, t1, 1, Bs_[3]);
    PH_SYNC(); MMA(1); PH_END();
    DS_A(0, 1, 0); DS_B(0, 1); stage(Ab, m0, t2, 0, As_[0]);
    PH_SYNC(); MMA(0); PH_END();
    DS_A(0, 1, 1);             stage(Bb, n0, t2, 0, Bs_[0]); VW(4);
    PH_SYNC(); MMA(1); PH_END();
    DS_A(1, 0, 0); DS_B(1, 0); stage(Ab, m0, t2, 1, As_[1]);
    PH_SYNC(); MMA(0); PH_END();
    DS_A(1, 0, 1);             stage(Bb, n0, t2, 1, Bs_[1]);
    PH_SYNC(); MMA(1); PH_END();
    DS_A(1, 1, 0); DS_B(1, 1); stage(Ab, m0, t3, 0, As_[2]);
    PH_SYNC(); MMA(0); PH_END();
    DS_A(1, 1, 1);             stage(Bb, n0, t3, 0, Bs_[2]); VW(4);
    PH_SYNC(); MMA(1); PH_END();
  }

  DS_A(0, 0, 0); DS_B(0, 0); stage(Ab, m0, 15, 1, As_[3]);
  PH_SYNC(); MMA(0); PH_END();
  DS_A(0, 0, 1);             stage(Bb, n0, 15, 1, Bs_[3]);
  PH_SYNC(); MMA(1); PH_END();
  DS_A(0, 1, 0); DS_B(0, 1);
  PH_SYNC(); MMA(0); PH_END();
  DS_A(0, 1, 1); VW(0);
  PH_SYNC(); MMA(1); PH_END();
  DS_A(1, 0, 0); DS_B(1, 0);
  PH_SYNC(); MMA(0); PH_END();
  DS_A(1, 0, 1);
  PH_SYNC(); MMA(1); PH_END();
  DS_A(1, 1, 0); DS_B(1, 1);
  PH_SYNC(); MMA(0); PH_END();
  DS_A(1, 1, 1);
  PH_SYNC(); MMA(1); PH_END();

  const int seg = n0 >> 10;
  const int nh0 = (n0 & 1023) + wno;
  float* dst = (seg == 0) ? zt : (seg == 1 ? Cf : Ho);
#pragma unroll
  for (int fj = 0; fj < 4; ++fj) {
    const int nn = nh0 + fj * 16 + lr;
    const float bv = bias[seg * 1024 + nn];
#pragma unroll
    for (int fi = 0; fi < 8; ++fi) {
#pragma unroll
      for (int rr = 0; rr < 4; ++rr) {
        const int mm = m0 + wmo + fi * 16 + lq * 4 + rr;
        const float v = acc[fi][fj][rr] + bv;
        dst[(size_t)mm * H_ + nn] = (seg == 0) ? tanh_(v) : sigmoid_(v);
      }
    }
  }
}

// =============================================================================
// Scan kernels: float4 channels (16 B/lane) + 1-deep software prefetch so each
// wave keeps the next iteration's loads in flight during the update stall.
// Per-channel op order identical to before -> bit-identical results.
// =============================================================================

// ---- scan pass A: per-chunk (prod(1-f), local c_end with c_in = 0) ----------
__global__ void scanA(const float* __restrict__ Cf, const float* __restrict__ zt,
                      float* __restrict__ ckA, float* __restrict__ ckC) {
  const int ch4 = blockIdx.x * 256 + threadIdx.x;   // float4 channel idx (0..2047)
  const int j   = blockIdx.y;
  const float4* Cf4 = (const float4*)Cf;
  const float4* zt4 = (const float4*)zt;
  size_t base = (size_t)j * T_ * (CH_ / 4) + ch4;
  float4 A = {1.f, 1.f, 1.f, 1.f}, c = {0.f, 0.f, 0.f, 0.f};
  float4 f = Cf4[base], z = zt4[base];
  for (int tt = 0; tt < T_ - 1; ++tt) {
    const float4 fn = Cf4[base + CH_ / 4];   // prefetch next step
    const float4 zn = zt4[base + CH_ / 4];
    float om;
    om = 1.f - f.x; c.x = f.x * z.x + om * c.x; A.x *= om;
    om = 1.f - f.y; c.y = f.y * z.y + om * c.y; A.y *= om;
    om = 1.f - f.z; c.z = f.z * z.z + om * c.z; A.z *= om;
    om = 1.f - f.w; c.w = f.w * z.w + om * c.w; A.w *= om;
    f = fn; z = zn; base += CH_ / 4;
  }
  {
    float om;
    om = 1.f - f.x; c.x = f.x * z.x + om * c.x; A.x *= om;
    om = 1.f - f.y; c.y = f.y * z.y + om * c.y; A.y *= om;
    om = 1.f - f.z; c.z = f.z * z.z + om * c.z; A.z *= om;
    om = 1.f - f.w; c.w = f.w * z.w + om * c.w; A.w *= om;
  }
  ((float4*)ckA)[(size_t)j * (CH_ / 4) + ch4] = A;
  ((float4*)ckC)[(size_t)j * (CH_ / 4) + ch4] = c;
}

// ---- scan combine: sequential over NC_ chunks, seeded with hidden -----------
__global__ void scanComb(const float* __restrict__ ckA, const float* __restrict__ ckC,
                         const float* __restrict__ hidden, float* __restrict__ carry) {
  const int ch4 = blockIdx.x * 64 + threadIdx.x;    // 32 blocks x 64 threads
  const float4* a4 = (const float4*)ckA;
  const float4* c4 = (const float4*)ckC;
  float4 c = ((const float4*)hidden)[ch4];
  for (int j = 0; j < NC_; ++j) {
    ((float4*)carry)[(size_t)j * (CH_ / 4) + ch4] = c;   // c entering chunk j
    const float4 Aj = a4[(size_t)j * (CH_ / 4) + ch4];
    const float4 Cj = c4[(size_t)j * (CH_ / 4) + ch4];
    c.x = Cj.x + Aj.x * c.x;
    c.y = Cj.y + Aj.y * c.y;
    c.z = Cj.z + Aj.z * c.z;
    c.w = Cj.w + Aj.w * c.w;
  }
}

// ---- scan pass B: replay with true carry; write C and H in place ------------
__global__ void scanB(float* __restrict__ Cf,          // in: sigm(F), out: C
                      const float* __restrict__ zt,    // tanh(Z)
                      float* __restrict__ Ho,          // in: sigm(O), out: H
                      float* __restrict__ Clast,       // [CH_]
                      const float* __restrict__ carry) {
  const int ch4 = blockIdx.x * 256 + threadIdx.x;
  const int j   = blockIdx.y;
  float4* Cf4 = (float4*)Cf;
  const float4* zt4 = (const float4*)zt;
  float4* Ho4 = (float4*)Ho;
  size_t base = (size_t)j * T_ * (CH_ / 4) + ch4;
  float4 c = ((const float4*)carry)[(size_t)j * (CH_ / 4) + ch4];
  float4 f = Cf4[base], z = zt4[base], o = Ho4[base];
  for (int tt = 0; tt < T_ - 1; ++tt) {
    const float4 fn = Cf4[base + CH_ / 4];   // prefetch next step
    const float4 zn = zt4[base + CH_ / 4];
    const float4 on = Ho4[base + CH_ / 4];
    c.x = f.x * z.x + (1.f - f.x) * c.x;
    c.y = f.y * z.y + (1.f - f.y) * c.y;
    c.z = f.z * z.z + (1.f - f.z) * c.z;
    c.w = f.w * z.w + (1.f - f.w) * c.w;
    Cf4[base] = c;
    Ho4[base] = float4{o.x * c.x, o.y * c.y, o.z * c.z, o.w * c.w};
    f = fn; z = zn; o = on; base += CH_ / 4;
  }
  c.x = f.x * z.x + (1.f - f.x) * c.x;
  c.y = f.y * z.y + (1.f - f.y) * c.y;
  c.z = f.z * z.z + (1.f - f.z) * c.z;
  c.w = f.w * z.w + (1.f - f.w) * c.w;
  Cf4[base] = c;
  Ho4[base] = float4{o.x * c.x, o.y * c.y, o.z * c.z, o.w * c.w};
  if (j == NC_ - 1) ((float4*)Clast)[ch4] = c;
}

extern "C" void kernel_launch(void* const* d_in, const int* in_sizes, int n_in,
                              void* d_out, int out_size, void* d_ws, size_t ws_size,
                              hipStream_t stream) {
  const float* X    = (const float*)d_in[0];   // [S,B,IN]
  const float* hid  = (const float*)d_in[1];   // [B,H]
  const float* W    = (const float*)d_in[2];   // [3H,IN]
  const float* bias = (const float*)d_in[3];   // [3H]

  float* out   = (float*)d_out;
  float* Ho    = out;                          // H       [S,B,H]
  float* Clast = out + (size_t)M_ * H_;        // C[-1:]  [1,B,H]
  float* Cf    = Clast + CH_;                  // C       [S,B,H]

  char* ws = (char*)d_ws;
  u16*  Xb    = (u16*)ws;                      //  67108864 B bf16 X
  u16*  Wb    = (u16*)(ws + 67108864);         //   6291456 B bf16 W
  float* zt   = (float*)(ws + 73400320);       // 134217728 B tanh(Z)
  float* ckA  = (float*)(ws + 207618048);      //   2097152 B
  float* ckC  = (float*)(ws + 209715200);      //   2097152 B
  float* carry= (float*)(ws + 211812352);      //   2097152 B  (total ~204 MiB)

  const int nAll = M_ * K_ / 8 + N_ * K_ / 8;
  cvt_all<<<(nAll + 255) / 256, 256, 0, stream>>>(X, W, Xb, Wb);
  gemm_act<<<dim3(N_ / 256, M_ / 256), 512, 0, stream>>>(Xb, Wb, bias, zt, Cf, Ho);
  scanA<<<dim3(CH_ / 1024, NC_), 256, 0, stream>>>(Cf, zt, ckA, ckC);
  scanComb<<<CH_ / 4 / 64, 64, 0, stream>>>(ckA, ckC, hid, carry);
  scanB<<<dim3(CH_ / 1024, NC_), 256, 0, stream>>>(Cf, zt, Ho, Clast, carry);
}